// Round 8
// baseline (141.920 us; speedup 1.0000x reference)
//
#include <hip/hip_runtime.h>
#include <hip/hip_bf16.h>
#include <cstdint>
#include <cmath>

#define B_ 512
#define T_ 256
#define C_ 256
#define HS_ 64

typedef short bf16x8 __attribute__((ext_vector_type(8)));
typedef float f32x4 __attribute__((ext_vector_type(4)));

static __device__ __forceinline__ unsigned short f2bf(float f) {
    union { float f; unsigned int u; } v; v.f = f;
    unsigned int r = v.u + 0x7fffu + ((v.u >> 16) & 1u);
    return (unsigned short)(r >> 16);
}

// ---- Kernel 0: W -> pre-fragmented bf16 WTf.
// fb = fid*8 + kap ; fid = ws*4+f ; WTf[fb*512 + l*8 + j] = W_ws[kap*32+(l>>4)*8+j][f*16+(l&15)]
__global__ void wt_kernel(const float* __restrict__ Wq, const float* __restrict__ Wk,
                          const float* __restrict__ Wv, unsigned short* __restrict__ WTf) {
    int idx = blockIdx.x * 256 + threadIdx.x;
    if (idx >= 96 * 64) return;
    int fb = idx >> 6;
    int l = idx & 63;
    int ws = fb >> 5;
    int rem = fb & 31;
    int f = rem >> 3;
    int kap = rem & 7;
    const float* W = (ws == 0) ? Wq : ((ws == 1) ? Wk : Wv);
    unsigned short o[8];
#pragma unroll
    for (int j = 0; j < 8; ++j) {
        int k = kap * 32 + (l >> 4) * 8 + j;
        int n = f * 16 + (l & 15);
        o[j] = f2bf(W[k * HS_ + n]);
    }
    *(ulonglong2*)(WTf + (size_t)idx * 8) = *(ulonglong2*)o;
}

// ---- Kernel 1: projection GEMM — stage-once, sync-once.
// Block: 256 thr / 4 waves, 64 token-rows, full K=256 in 32 KB LDS (bf16, swizzled).
// Staging: coalesced float4 loads (reg) -> f2bf -> ds_write_b64. ONE barrier.
// Compute: wave owns 16 rows x all 12 fragments; B-frags stream from WTf (L1/L2-hot).
// Pipelining comes from 4-5 blocks/CU overlapping (no intra-block drain points).
__global__ __launch_bounds__(256, 4)
void proj_kernel(const float* __restrict__ x, const unsigned short* __restrict__ WTf,
                 unsigned short* __restrict__ Qb, unsigned short* __restrict__ Kb,
                 unsigned short* __restrict__ Vt) {
    __shared__ __align__(16) char xt[32768];     // [64 rows][256 bf16], swizzled
    const int tid = threadIdx.x;
    const int w = tid >> 6;
    const int l = tid & 63;
    const int ln = l & 15;
    const int lg = l >> 4;
    const int m0 = blockIdx.x * 64;
    const float* xb = x + (size_t)m0 * C_;

    // ---- stage: 16 float4 per thread, fully coalesced ----
#pragma unroll
    for (int i = 0; i < 16; ++i) {
        const int fidx = i * 256 + tid;           // float4 index in tile
        const int row = fidx >> 6;
        const int c4 = (fidx & 63) * 4;           // float col
        float4 v = *(const float4*)(xb + (size_t)row * C_ + c4);
        ushort4 hh;
        hh.x = f2bf(v.x); hh.y = f2bf(v.y); hh.z = f2bf(v.z); hh.w = f2bf(v.w);
        *(ushort4*)(xt + row * 512 + ((c4 * 2) ^ ((row & 7) << 4))) = hh;
    }
    __syncthreads();     // the ONLY barrier

    f32x4 acc[12];
#pragma unroll
    for (int a = 0; a < 12; ++a) acc[a] = (f32x4){0.f, 0.f, 0.f, 0.f};

    const int R = w * 16 + ln;                    // this lane's token row (as B-frag col)
#pragma unroll
    for (int kap = 0; kap < 8; ++kap) {
        bf16x8 afr = *(const bf16x8*)(xt + R * 512
                      + ((kap * 64 + lg * 16) ^ ((R & 7) << 4)));
#pragma unroll
        for (int fid = 0; fid < 12; ++fid) {
            bf16x8 bfr = *(const bf16x8*)(WTf + ((size_t)(fid * 8 + kap) * 64 + l) * 8);
            acc[fid] = __builtin_amdgcn_mfma_f32_16x16x32_bf16(bfr, afr, acc[fid], 0, 0, 0);
        }
    }

    // ---- epilogue: direct stores. token = m0+R, feature = f*16 + lg*4 + r ----
    const int row = m0 + R;
#pragma unroll
    for (int ws_ = 0; ws_ < 2; ++ws_) {
        unsigned short* gdst = (ws_ == 0) ? Qb : Kb;
#pragma unroll
        for (int f = 0; f < 4; ++f) {
            f32x4 a = acc[ws_ * 4 + f];
            ushort4 o;
            o.x = f2bf(a[0]); o.y = f2bf(a[1]); o.z = f2bf(a[2]); o.w = f2bf(a[3]);
            *(ushort4*)(gdst + (size_t)row * HS_ + f * 16 + lg * 4) = o;
        }
    }
    {   // V transposed: Vt[batch][feat][token]
        unsigned short* gdst = Vt + (size_t)(row >> 8) * 16384 + (row & 255);
#pragma unroll
        for (int f = 0; f < 4; ++f)
#pragma unroll
            for (int i = 0; i < 4; ++i)
                gdst[(size_t)(f * 16 + lg * 4 + i) * 256] = f2bf(acc[8 + f][i]);
    }
}

// ---- Kernel 2: flash-style causal attention (V pre-transposed; round-5 proven) ----
__global__ __launch_bounds__(256)
void attn_kernel(const unsigned short* __restrict__ Qb, const unsigned short* __restrict__ Kb,
                 const unsigned short* __restrict__ Vt, float* __restrict__ out) {
    __shared__ unsigned short P_lds[4][16][40];

    const int w = threadIdx.x >> 6;
    const int l = threadIdx.x & 63;
    const int ln = l & 15;
    const int lg = l >> 4;
    const int b = blockIdx.x >> 2;
    const int qt = blockIdx.x & 3;
    const int q0 = qt * 64;
    const int r0 = q0 + w * 16;
    const size_t base = (size_t)b * T_ * HS_;
    const size_t vbase = (size_t)b * HS_ * T_;       // Vt: [64][256] per batch
    const float scale = 0.0625f;

    bf16x8 qa[2];
#pragma unroll
    for (int kk = 0; kk < 2; ++kk)
        qa[kk] = *(const bf16x8*)(Qb + base + (size_t)(r0 + ln) * HS_ + kk * 32 + lg * 8);

    float m[4], lsum[4];
    f32x4 o[4];
#pragma unroll
    for (int r = 0; r < 4; ++r) { m[r] = -INFINITY; lsum[r] = 0.f; }
#pragma unroll
    for (int f = 0; f < 4; ++f) o[f] = (f32x4){0.f, 0.f, 0.f, 0.f};

    const int nkt = qt * 2 + 2;
    for (int kt = 0; kt < nkt; ++kt) {
        const int n0 = kt * 32;

        f32x4 s[2];
#pragma unroll
        for (int h = 0; h < 2; ++h) {
            bf16x8 kb0 = *(const bf16x8*)(Kb + base + (size_t)(n0 + 16 * h + ln) * HS_ + lg * 8);
            bf16x8 kb1 = *(const bf16x8*)(Kb + base + (size_t)(n0 + 16 * h + ln) * HS_ + 32 + lg * 8);
            f32x4 z = (f32x4){0.f, 0.f, 0.f, 0.f};
            z = __builtin_amdgcn_mfma_f32_16x16x32_bf16(qa[0], kb0, z, 0, 0, 0);
            s[h] = __builtin_amdgcn_mfma_f32_16x16x32_bf16(qa[1], kb1, z, 0, 0, 0);
        }

        float sm[2][4];
#pragma unroll
        for (int r = 0; r < 4; ++r) {
            const int qrow = r0 + lg * 4 + r;
#pragma unroll
            for (int h = 0; h < 2; ++h) {
                float v = s[h][r] * scale;
                sm[h][r] = (qrow >= n0 + 16 * h + ln) ? v : -INFINITY;
            }
        }

        float fac[4], p[2][4];
#pragma unroll
        for (int r = 0; r < 4; ++r) {
            float tmax = fmaxf(sm[0][r], sm[1][r]);
#pragma unroll
            for (int mask = 1; mask < 16; mask <<= 1)
                tmax = fmaxf(tmax, __shfl_xor(tmax, mask, 64));
            float mn = fmaxf(m[r], tmax);
            fac[r] = __expf(m[r] - mn);
            p[0][r] = __expf(sm[0][r] - mn);
            p[1][r] = __expf(sm[1][r] - mn);
            float rs = p[0][r] + p[1][r];
#pragma unroll
            for (int mask = 1; mask < 16; mask <<= 1)
                rs += __shfl_xor(rs, mask, 64);
            lsum[r] = lsum[r] * fac[r] + rs;
            m[r] = mn;
        }
#pragma unroll
        for (int f = 0; f < 4; ++f)
#pragma unroll
            for (int r = 0; r < 4; ++r)
                o[f][r] *= fac[r];

#pragma unroll
        for (int h = 0; h < 2; ++h)
#pragma unroll
            for (int r = 0; r < 4; ++r)
                P_lds[w][lg * 4 + r][16 * h + ln] = f2bf(p[h][r]);

        bf16x8 pa = *(const bf16x8*)(&P_lds[w][ln][lg * 8]);

#pragma unroll
        for (int f = 0; f < 4; ++f) {
            bf16x8 vb = *(const bf16x8*)(Vt + vbase + (size_t)(f * 16 + ln) * T_ + n0 + lg * 8);
            o[f] = __builtin_amdgcn_mfma_f32_16x16x32_bf16(pa, vb, o[f], 0, 0, 0);
        }
    }

#pragma unroll
    for (int f = 0; f < 4; ++f)
#pragma unroll
        for (int r = 0; r < 4; ++r) {
            int trow = r0 + lg * 4 + r;
            out[base + (size_t)trow * HS_ + 16 * f + ln] = o[f][r] / lsum[r];
        }
}

extern "C" void kernel_launch(void* const* d_in, const int* in_sizes, int n_in,
                              void* d_out, int out_size, void* d_ws, size_t ws_size,
                              hipStream_t stream) {
    const float* x  = (const float*)d_in[0];
    const float* Wq = (const float*)d_in[1];
    const float* Wk = (const float*)d_in[2];
    const float* Wv = (const float*)d_in[3];
    float* out = (float*)d_out;

    unsigned short* WTf = (unsigned short*)d_ws;                // 96 KB
    unsigned short* Qb = WTf + 96 * 64 * 8;
    unsigned short* Kb = Qb + (size_t)B_ * T_ * HS_;
    unsigned short* Vt = Kb + (size_t)B_ * T_ * HS_;

    wt_kernel<<<24, 256, 0, stream>>>(Wq, Wk, Wv, WTf);
    proj_kernel<<<(B_ * T_) / 64, 256, 0, stream>>>(x, WTf, Qb, Kb, Vt);
    attn_kernel<<<B_ * 4, 256, 0, stream>>>(Qb, Kb, Vt, out);
}

// Round 9
// 69.925 us; speedup vs baseline: 2.0296x; 2.0296x over previous
//
#include <hip/hip_runtime.h>
#include <hip/hip_bf16.h>
#include <cstdint>
#include <cmath>

#define B_ 512
#define T_ 256
#define C_ 256
#define HS_ 64

typedef short bf16x8 __attribute__((ext_vector_type(8)));
typedef float f32x4 __attribute__((ext_vector_type(4)));

static __device__ __forceinline__ unsigned short f2bf(float f) {
    union { float f; unsigned int u; } v; v.f = f;
    unsigned int r = v.u + 0x7fffu + ((v.u >> 16) & 1u);
    return (unsigned short)(r >> 16);
}

static __device__ __forceinline__ uint2 pack4(f32x4 a) {
    uint2 r;
    r.x = (unsigned)f2bf(a[0]) | ((unsigned)f2bf(a[1]) << 16);
    r.y = (unsigned)f2bf(a[2]) | ((unsigned)f2bf(a[3]) << 16);
    return r;
}

// ---- Kernel 0: W -> pre-fragmented bf16 WTf.
// fb = fid*8 + kap ; fid = ws*4+f ; WTf[fb*512 + l*8 + j] = W_ws[kap*32+(l>>4)*8+j][f*16+(l&15)]
__global__ void wt_kernel(const float* __restrict__ Wq, const float* __restrict__ Wk,
                          const float* __restrict__ Wv, unsigned short* __restrict__ WTf) {
    int idx = blockIdx.x * 256 + threadIdx.x;
    if (idx >= 96 * 64) return;
    int fb = idx >> 6;
    int l = idx & 63;
    int ws = fb >> 5;
    int rem = fb & 31;
    int f = rem >> 3;
    int kap = rem & 7;
    const float* W = (ws == 0) ? Wq : ((ws == 1) ? Wk : Wv);
    unsigned short o[8];
#pragma unroll
    for (int j = 0; j < 8; ++j) {
        int k = kap * 32 + (l >> 4) * 8 + j;
        int n = f * 16 + (l & 15);
        o[j] = f2bf(W[k * HS_ + n]);
    }
    *(ulonglong2*)(WTf + (size_t)idx * 8) = *(ulonglong2*)o;
}

// ---- Fused kernel: one block per batch. 512 threads / 8 waves. 160 KB static LDS.
// [0,96K):  W-lds (phase 1) -> overwritten by Q[32K)/K[32K)/Vt[32K) (phase 1.5/2)
// [96K,160K): x slab buffer [128 rows][512 B bf16] (phase 2: per-wave P tiles)
// Swizzle everywhere: in-row byte ^= (row&7)<<4.
__global__ __launch_bounds__(512, 2)
void fused_kernel(const float* __restrict__ x, const unsigned short* __restrict__ WTf,
                  float* __restrict__ out) {
    __shared__ __align__(16) char smem[163840];
    unsigned short* Qs  = (unsigned short*)(smem);
    unsigned short* Ks  = (unsigned short*)(smem + 32768);
    unsigned short* Vts = (unsigned short*)(smem + 65536);
    char* xbuf = smem + 98304;

    const int tid = threadIdx.x;
    const int w = tid >> 6, l = tid & 63, ln = l & 15, lg = l >> 4;
    const int b = blockIdx.x;
    const float* xb = x + (size_t)b * (T_ * C_);
    const int fidbase = 3 * (w >> 1);      // this wave's 3 fragment-cols
    const int Tb = (w & 1) * 4;            // this wave's 4 row-tiles (of 8 in slab)

    // ---- prologue: W -> LDS, linear (dest = wave-uniform + lane*16) ----
#pragma unroll
    for (int r = 0; r < 12; ++r)
        __builtin_amdgcn_global_load_lds(
            (const __attribute__((address_space(1))) void*)((const char*)WTf + r * 8192 + tid * 16),
            (__attribute__((address_space(3))) void*)(smem + r * 8192 + tid * 16), 16, 0, 0);

    // slab-0 x loads (coalesced float4)
    float4 st[16];
#pragma unroll
    for (int i = 0; i < 16; ++i)
        st[i] = *(const float4*)(xb + (size_t)(i * 512 + tid) * 4);

    uint2 h0[12], h1[12];

#define DS_WRITE_SLAB() do { \
    _Pragma("unroll") \
    for (int i_ = 0; i_ < 16; ++i_) { \
        const int fidx_ = i_ * 512 + tid, row_ = fidx_ >> 6, c4_ = (fidx_ & 63) * 4; \
        ushort4 hh_; \
        hh_.x = f2bf(st[i_].x); hh_.y = f2bf(st[i_].y); \
        hh_.z = f2bf(st[i_].z); hh_.w = f2bf(st[i_].w); \
        *(ushort4*)(xbuf + row_ * 512 + ((c4_ * 2) ^ ((row_ & 7) << 4))) = hh_; \
    } \
} while (0)

#define SLAB_COMPUTE(H) do { \
    f32x4 acc_[12]; \
    _Pragma("unroll") \
    for (int k_ = 0; k_ < 12; ++k_) acc_[k_] = (f32x4){0.f, 0.f, 0.f, 0.f}; \
    _Pragma("unroll") \
    for (int kap_ = 0; kap_ < 8; ++kap_) { \
        bf16x8 bfr_[3]; \
        _Pragma("unroll") \
        for (int j_ = 0; j_ < 3; ++j_) \
            bfr_[j_] = *(const bf16x8*)(smem + (size_t)((fidbase + j_) * 8 + kap_) * 1024 + l * 16); \
        _Pragma("unroll") \
        for (int tt_ = 0; tt_ < 4; ++tt_) { \
            const int R_ = (Tb + tt_) * 16 + ln; \
            bf16x8 afr_ = *(const bf16x8*)(xbuf + R_ * 512 \
                           + ((kap_ * 64 + lg * 16) ^ ((R_ & 7) << 4))); \
            _Pragma("unroll") \
            for (int j_ = 0; j_ < 3; ++j_) \
                acc_[tt_ * 3 + j_] = __builtin_amdgcn_mfma_f32_16x16x32_bf16( \
                    bfr_[j_], afr_, acc_[tt_ * 3 + j_], 0, 0, 0); \
        } \
    } \
    _Pragma("unroll") \
    for (int k_ = 0; k_ < 12; ++k_) H[k_] = pack4(acc_[k_]); \
} while (0)

    // ---- slab 0 ----
    DS_WRITE_SLAB();            // compiler waits vmcnt for st (drains W gll too)
    __syncthreads();
#pragma unroll
    for (int i = 0; i < 16; ++i)   // prefetch slab 1 under slab-0 compute
        st[i] = *(const float4*)(xb + 32768 + (size_t)(i * 512 + tid) * 4);
    SLAB_COMPUTE(h0);
    __syncthreads();            // all reads of xbuf done

    // ---- slab 1 ----
    DS_WRITE_SLAB();
    __syncthreads();
    SLAB_COMPUTE(h1);
    __syncthreads();            // all W-lds reads done; region reusable

    // ---- phase 1.5: QKV regs -> LDS (overwrites W region) ----
#pragma unroll
    for (int s = 0; s < 2; ++s) {
#pragma unroll
        for (int tt = 0; tt < 4; ++tt)
#pragma unroll
            for (int j = 0; j < 3; ++j) {
                uint2 hv = s ? h1[tt * 3 + j] : h0[tt * 3 + j];
                const int token = s * 128 + (Tb + tt) * 16 + ln;
                const int fid = fidbase + j, f = fid & 3;
                if (fid < 8) {
                    unsigned short* base_ = (fid < 4) ? Qs : Ks;
                    *(uint2*)((char*)base_ + token * 128
                              + ((f * 32 + lg * 8) ^ ((token & 7) << 4))) = hv;
                } else {
                    unsigned short v4[4] = {
                        (unsigned short)(hv.x & 0xffff), (unsigned short)(hv.x >> 16),
                        (unsigned short)(hv.y & 0xffff), (unsigned short)(hv.y >> 16)};
#pragma unroll
                    for (int i = 0; i < 4; ++i) {
                        const int vr = f * 16 + lg * 4 + i;
                        *(unsigned short*)((char*)Vts + vr * 512
                              + ((token * 2) ^ ((vr & 7) << 4))) = v4[i];
                    }
                }
            }
    }
    __syncthreads();

    // ---- phase 2: causal attention from LDS (per-wave, barrier-free) ----
    unsigned short* Pl = (unsigned short*)(xbuf + w * 1280);   // [16][40] per wave
    float* outb = out + (size_t)b * (T_ * HS_);
    const float scale = 0.0625f;    // C^-0.5

#pragma unroll
    for (int pass = 0; pass < 2; ++pass) {
        const int g = pass ? (15 - w) : w;
        const int r0 = g * 16;

        bf16x8 qa[2];
#pragma unroll
        for (int kk = 0; kk < 2; ++kk)
            qa[kk] = *(const bf16x8*)((char*)Qs + (r0 + ln) * 128
                       + ((kk * 64 + lg * 16) ^ ((ln & 7) << 4)));

        float m[4], lsum[4];
        f32x4 o[4];
#pragma unroll
        for (int r = 0; r < 4; ++r) { m[r] = -INFINITY; lsum[r] = 0.f; }
#pragma unroll
        for (int f = 0; f < 4; ++f) o[f] = (f32x4){0.f, 0.f, 0.f, 0.f};

        const int nkt = (g >> 1) + 1;
        for (int kt = 0; kt < nkt; ++kt) {
            const int n0 = kt * 32;

            f32x4 s2[2];
#pragma unroll
            for (int h = 0; h < 2; ++h) {
                const int key = n0 + 16 * h + ln;
                bf16x8 kb0 = *(const bf16x8*)((char*)Ks + key * 128
                               + ((lg * 16) ^ ((key & 7) << 4)));
                bf16x8 kb1 = *(const bf16x8*)((char*)Ks + key * 128
                               + ((64 + lg * 16) ^ ((key & 7) << 4)));
                f32x4 z = (f32x4){0.f, 0.f, 0.f, 0.f};
                z = __builtin_amdgcn_mfma_f32_16x16x32_bf16(qa[0], kb0, z, 0, 0, 0);
                s2[h] = __builtin_amdgcn_mfma_f32_16x16x32_bf16(qa[1], kb1, z, 0, 0, 0);
            }

            float sm[2][4];
#pragma unroll
            for (int r = 0; r < 4; ++r) {
                const int qrow = r0 + lg * 4 + r;
#pragma unroll
                for (int h = 0; h < 2; ++h) {
                    float v = s2[h][r] * scale;
                    sm[h][r] = (qrow >= n0 + 16 * h + ln) ? v : -INFINITY;
                }
            }

            float fac[4], p[2][4];
#pragma unroll
            for (int r = 0; r < 4; ++r) {
                float tmax = fmaxf(sm[0][r], sm[1][r]);
#pragma unroll
                for (int mask = 1; mask < 16; mask <<= 1)
                    tmax = fmaxf(tmax, __shfl_xor(tmax, mask, 64));
                float mn = fmaxf(m[r], tmax);
                fac[r] = __expf(m[r] - mn);
                p[0][r] = __expf(sm[0][r] - mn);
                p[1][r] = __expf(sm[1][r] - mn);
                float rs = p[0][r] + p[1][r];
#pragma unroll
                for (int mask = 1; mask < 16; mask <<= 1)
                    rs += __shfl_xor(rs, mask, 64);
                lsum[r] = lsum[r] * fac[r] + rs;
                m[r] = mn;
            }
#pragma unroll
            for (int f = 0; f < 4; ++f)
#pragma unroll
                for (int r = 0; r < 4; ++r)
                    o[f][r] *= fac[r];

#pragma unroll
            for (int h = 0; h < 2; ++h)
#pragma unroll
                for (int r = 0; r < 4; ++r)
                    Pl[(lg * 4 + r) * 40 + 16 * h + ln] = f2bf(p[h][r]);

            bf16x8 pa = *(const bf16x8*)(Pl + ln * 40 + lg * 8);

#pragma unroll
            for (int f = 0; f < 4; ++f) {
                const int vr = f * 16 + ln;
                bf16x8 vb = *(const bf16x8*)((char*)Vts + vr * 512
                              + ((n0 * 2 + lg * 16) ^ ((ln & 7) << 4)));
                o[f] = __builtin_amdgcn_mfma_f32_16x16x32_bf16(pa, vb, o[f], 0, 0, 0);
            }
        }

#pragma unroll
        for (int f = 0; f < 4; ++f)
#pragma unroll
            for (int r = 0; r < 4; ++r) {
                const int trow = r0 + lg * 4 + r;
                outb[(size_t)trow * HS_ + f * 16 + ln] = o[f][r] / lsum[r];
            }
    }
}

extern "C" void kernel_launch(void* const* d_in, const int* in_sizes, int n_in,
                              void* d_out, int out_size, void* d_ws, size_t ws_size,
                              hipStream_t stream) {
    const float* x  = (const float*)d_in[0];
    const float* Wq = (const float*)d_in[1];
    const float* Wk = (const float*)d_in[2];
    const float* Wv = (const float*)d_in[3];
    float* out = (float*)d_out;

    unsigned short* WTf = (unsigned short*)d_ws;     // 96 KB

    wt_kernel<<<24, 256, 0, stream>>>(Wq, Wk, Wv, WTf);
    fused_kernel<<<B_, 512, 0, stream>>>(x, WTf, out);
}